// Round 12
// baseline (467.997 us; speedup 1.0000x reference)
//
#include <hip/hip_runtime.h>
#include <hip/hip_bf16.h>
#include <math.h>

// Shapes: grd (N=64,C=64,24,24), sat (M=64,C=64,64,64); crop sat[:,:,12:52,12:52] (40x40)
// corr (64,64,17,17); out: [0,4096) similarity f32, [4096,40960) sat_f (64,24,24) f32.
//
// Pipeline: satT/grdT2 bf16 hi-lo transforms -> MFMA implicit-GEMM corr (3-product
// bf16x2, fp32-class accuracy; sat window in LDS read-only, B operands direct
// global->register with 1-iter prefetch, NO per-iteration barrier) -> argmax -> sim.

typedef float f32x4 __attribute__((ext_vector_type(4)));
typedef short short8 __attribute__((ext_vector_type(8)));

// ws layout (float words)
#define SATT_HI 0u          // bf16 [m][40*40 pix][64 c]
#define SATT_LO 3276800u
#define GRDT_HI 6553600u    // bf16 [ij=576][n=64][c=64]
#define GRDT_LO 7733248u
#define CORR_O  8912896u    // f32 [m][304][64]
#define WIN2_O  10158080u   // f32 [m][289]
#define GN2_O   10176576u   // f32 [64]
#define IDX_O   10176640u   // int [4096]

// LDS bank swizzle: rows are 64 B apart; XOR chunk bits (6:4) with row bits (9:7).
// Bijective involution; 16-consecutive-row b128 access -> each 16B chunk hit 2x = free.
#define SWZ(off) ((off) ^ ((((off) >> 7) & 7) << 4))

// ---------- T1: satT hi/lo, channel-last. grid 2560 = (m, r); block 256 ----------
__global__ __launch_bounds__(256) void make_satT(const float* __restrict__ sat,
                                                 __hip_bfloat16* __restrict__ sth,
                                                 __hip_bfloat16* __restrict__ stl) {
    __shared__ __hip_bfloat16 th[40 * 66], tl[40 * 66];
    int m = blockIdx.x / 40, r = blockIdx.x % 40;
    int tid = threadIdx.x;
    const float* base = sat + (size_t)m * 262144 + (12 + r) * 64 + 12;
    for (int k = 0; k < 10; k++) {
        int idx = tid + 256 * k;          // 2560 = 64c * 40w
        int c = idx / 40, w2 = idx % 40;
        float v = base[c * 4096 + w2];
        __hip_bfloat16 h = __float2bfloat16(v);
        __hip_bfloat16 lo = __float2bfloat16(v - __bfloat162float(h));
        th[w2 * 66 + c] = h;
        tl[w2 * 66 + c] = lo;
    }
    __syncthreads();
    __hip_bfloat16* dh = sth + (size_t)m * 102400 + r * 2560;
    __hip_bfloat16* dl = stl + (size_t)m * 102400 + r * 2560;
    for (int k = 0; k < 10; k++) {
        int idx = tid + 256 * k;          // idx = w*64 + c
        int w2 = idx >> 6, c = idx & 63;
        dh[idx] = th[w2 * 66 + c];
        dl[idx] = tl[w2 * 66 + c];
    }
}

// ---------- T2: grdT2 [ij][n][c] hi/lo. grid 256 = (n, c-half, hi/lo); block 256 ----------
__global__ __launch_bounds__(256) void make_grdT(const float* __restrict__ grd,
                                                 __hip_bfloat16* __restrict__ gth,
                                                 __hip_bfloat16* __restrict__ gtl) {
    __shared__ __hip_bfloat16 t[32 * 577];
    int bid = blockIdx.x;
    int n = bid >> 2, ch = (bid >> 1) & 1, hl = bid & 1;
    int tid = threadIdx.x;
    const float* src = grd + (size_t)n * 36864 + ch * 32 * 576;
    for (int k = 0; k < 72; k++) {
        int idx = tid + 256 * k;          // idx = cl*576 + ij
        int cl = idx / 576, ij = idx % 576;
        float v = src[idx];
        __hip_bfloat16 h = __float2bfloat16(v);
        t[cl * 577 + ij] = hl ? __float2bfloat16(v - __bfloat162float(h)) : h;
    }
    __syncthreads();
    __hip_bfloat16* dst = hl ? gtl : gth;
    for (int k = 0; k < 72; k++) {
        int idx = tid + 256 * k;          // idx = ij*32 + cl
        int ij = idx >> 5, cl = idx & 31;
        dst[(size_t)ij * 4096 + n * 64 + ch * 32 + cl] = t[cl * 577 + ij];
    }
}

// ---------- N1: patch-window norms^2 via separable sums. grid 64 (m) ----------
__global__ __launch_bounds__(256) void make_win2(const float* __restrict__ sat,
                                                 float* __restrict__ win2) {
    __shared__ float S2[40][41];
    __shared__ float RS[40][18];
    int m = blockIdx.x, tid = threadIdx.x;
    const float* base = sat + (size_t)m * 262144;
    for (int k = 0; k < 7; k++) {
        int idx = tid + 256 * k;
        if (idx < 1600) {
            int r = idx / 40, w2 = idx % 40;
            float s = 0.0f;
            for (int c = 0; c < 64; c++) {
                float v = base[c * 4096 + (12 + r) * 64 + 12 + w2];
                s += v * v;
            }
            S2[r][w2] = s;
        }
    }
    __syncthreads();
    for (int k = 0; k < 3; k++) {
        int idx = tid + 256 * k;
        if (idx < 680) {
            int r = idx / 17, x = idx % 17;
            float s = 0.0f;
            for (int j = 0; j < 24; j++) s += S2[r][x + j];
            RS[r][x] = s;
        }
    }
    __syncthreads();
    for (int k = 0; k < 2; k++) {
        int idx = tid + 256 * k;
        if (idx < 289) {
            int y = idx / 17, x = idx % 17;
            float s = 0.0f;
            for (int i2 = 0; i2 < 24; i2++) s += RS[y + i2][x];
            win2[m * 289 + idx] = s;
        }
    }
}

// ---------- N2: ||grd_n||^2. grid 64 (n) ----------
__global__ __launch_bounds__(256) void make_gn2(const float* __restrict__ grd,
                                                float* __restrict__ gn2) {
    int n = blockIdx.x, tid = threadIdx.x;
    const float* g = grd + (size_t)n * 36864;
    float s = 0.0f;
    for (int k = 0; k < 144; k++) {
        float v = g[tid + 256 * k];
        s += v * v;
    }
    for (int off = 32; off; off >>= 1) s += __shfl_down(s, off);
    __shared__ float red[4];
    if ((tid & 63) == 0) red[tid >> 6] = s;
    __syncthreads();
    if (tid == 0) gn2[n] = red[0] + red[1] + red[2] + red[3];
}

// ---------- K1: MFMA corr. grid 512; block 512 = 8 waves; 2 blocks/CU ----------
// Round-10 post-mortem: MfmaUtil pinned at ~51% at BOTH 2 and 4 waves/SIMD ->
// the limiter is the per-iteration __syncthreads() (emits vmcnt(0)+lgkmcnt(0),
// draining the same-iteration global B prefetch; all 16 waves/CU sync in
// lockstep so nothing covers the drain). This round: B operands move from LDS
// to REGISTERS (each wave loads its own 2 n-tile fragments direct from global;
// 4 waves per half read identical addresses -> L1 broadcast), prefetched one
// iteration ahead into named regs. satW is LDS read-only during the 72-iter
// loop -> NO barrier inside the loop; barriers only at the 8 satW restage
// points. Inner loop is pure dataflow: compiler pipelines vmcnt/lgkmcnt.
// Wave w: p-tiles {w&3, +4, +8, +12, +16} x 2 n-tiles (nb=(w>>2)*2); tile 19
// is a ghost (loads clamp to p=288, stores guarded). Per c-chunk (2x32):
// hi-pass (ah*bh + ah*bl), lo-pass (al*bh); acc (5x2 f32x4) persists in AGPRs.
// satW accesses SWZ-swizzled (write+read same involution).
__global__ __launch_bounds__(512, 4) void corr_mfma(const __hip_bfloat16* __restrict__ sth,
                                                    const __hip_bfloat16* __restrict__ stl,
                                                    const __hip_bfloat16* __restrict__ gth,
                                                    const __hip_bfloat16* __restrict__ gtl,
                                                    float* __restrict__ corr) {
    __shared__ __align__(16) __hip_bfloat16 satW[760 * 32];     // 48,640 B

    int bid = blockIdx.x;
    int xcd = bid & 7, slot = bid >> 3;            // slot 0..63
    int m = xcd * 8 + (slot >> 3), iq = slot & 7;  // 8 m per XCD, 8 i-slices per m
    int tid = threadIdx.x;
    int w = tid >> 6, l = tid & 63, r = l & 15, g = l >> 4;
    int wl = w & 3;                 // p-tile group
    int nb = (w >> 2) * 2;          // first n-tile (0 or 2)

    int rowbase[5];
#pragma unroll
    for (int k = 0; k < 5; k++) {
        int p = 16 * (wl + 4 * k) + r;
        if (p > 288) p = 288;                 // ghost rows read a valid pixel
        rowbase[k] = (p / 17) * 40 + (p % 17);
    }
    f32x4 acc[5][2];
#pragma unroll
    for (int k = 0; k < 5; k++)
#pragma unroll
        for (int j = 0; j < 2; j++) acc[k][j] = (f32x4)0.0f;

    // satT source: [m][pix][64c]; window pixel wp (0..759) -> elem offset
    // m*102400 + iq*7680 + wp*64 (+cc*32).
    const __hip_bfloat16* sat_hi = sth + (size_t)m * 102400 + iq * 7680;
    const __hip_bfloat16* sat_lo = stl + (size_t)m * 102400 + iq * 7680;

    // B fragment base (per-lane): gth/gtl[ijg=iq*72+ijl][ (nt*16+r)*64 + cc*32 + g*8 ].
    size_t bfrag = (size_t)(iq * 72) * 4096 + (nb * 16 + r) * 64 + g * 8;
    const __hip_bfloat16* bh_base = gth + bfrag;
    const __hip_bfloat16* bl_base = gtl + bfrag;

    // satW stage: 3040 16-B slots; idx -> pix=idx>>2, seg=idx&3; dst = SWZ(idx*16).
#define STAGE_SAT(SRC, CC) {                                                   \
        const __hip_bfloat16* sp_ = (SRC) + (CC) * 32;                         \
        _Pragma("unroll")                                                      \
        for (int k2 = 0; k2 < 6; k2++) {                                       \
            int idx = tid + 512 * k2;                                          \
            if (idx < 3040) {                                                  \
                float4 v = *(const float4*)(sp_ + (idx >> 2) * 64 + (idx & 3) * 8); \
                *(float4*)((char*)satW + SWZ(idx * 16)) = v;                   \
            }                                                                  \
        }                                                                      \
    }

#pragma unroll
    for (int cc = 0; cc < 2; cc++) {
        const int ccoff = cc * 32;
        // ================= hi pass: acc += ah*bh + ah*bl =================
        __syncthreads();                       // all waves done reading satW
        STAGE_SAT(sat_hi, cc);
        __syncthreads();
        {
            short8 n0h = *(const short8*)(bh_base + ccoff);
            short8 n1h = *(const short8*)(bh_base + ccoff + 1024);
            short8 n0l = *(const short8*)(bl_base + ccoff);
            short8 n1l = *(const short8*)(bl_base + ccoff + 1024);
            for (int ijl = 0; ijl < 72; ijl++) {
                short8 b0h = n0h, b1h = n1h, b0l = n0l, b1l = n1l;
                if (ijl + 1 < 72) {
                    const __hip_bfloat16* ph = bh_base + ccoff + (size_t)(ijl + 1) * 4096;
                    const __hip_bfloat16* pl = bl_base + ccoff + (size_t)(ijl + 1) * 4096;
                    n0h = *(const short8*)ph;
                    n1h = *(const short8*)(ph + 1024);
                    n0l = *(const short8*)pl;
                    n1l = *(const short8*)(pl + 1024);
                }
                int il = ijl / 24, jj = ijl - il * 24;
                int pixoff = il * 40 + jj;

                short8 a0[5];
#pragma unroll
                for (int k = 0; k < 5; k++) {
                    int ao = (rowbase[k] + pixoff) * 64 + g * 16;
                    a0[k] = *(const short8*)((const char*)satW + SWZ(ao));
                }
#pragma unroll
                for (int k = 0; k < 5; k++) {
                    acc[k][0] = __builtin_amdgcn_mfma_f32_16x16x32_bf16(a0[k], b0h, acc[k][0], 0, 0, 0);
                    acc[k][0] = __builtin_amdgcn_mfma_f32_16x16x32_bf16(a0[k], b0l, acc[k][0], 0, 0, 0);
                    acc[k][1] = __builtin_amdgcn_mfma_f32_16x16x32_bf16(a0[k], b1h, acc[k][1], 0, 0, 0);
                    acc[k][1] = __builtin_amdgcn_mfma_f32_16x16x32_bf16(a0[k], b1l, acc[k][1], 0, 0, 0);
                }
            }
        }
        // ================= lo pass: acc += al*bh =================
        __syncthreads();
        STAGE_SAT(sat_lo, cc);
        __syncthreads();
        {
            short8 n0h = *(const short8*)(bh_base + ccoff);
            short8 n1h = *(const short8*)(bh_base + ccoff + 1024);
            for (int ijl = 0; ijl < 72; ijl++) {
                short8 b0h = n0h, b1h = n1h;
                if (ijl + 1 < 72) {
                    const __hip_bfloat16* ph = bh_base + ccoff + (size_t)(ijl + 1) * 4096;
                    n0h = *(const short8*)ph;
                    n1h = *(const short8*)(ph + 1024);
                }
                int il = ijl / 24, jj = ijl - il * 24;
                int pixoff = il * 40 + jj;

                short8 a0[5];
#pragma unroll
                for (int k = 0; k < 5; k++) {
                    int ao = (rowbase[k] + pixoff) * 64 + g * 16;
                    a0[k] = *(const short8*)((const char*)satW + SWZ(ao));
                }
#pragma unroll
                for (int k = 0; k < 5; k++) {
                    acc[k][0] = __builtin_amdgcn_mfma_f32_16x16x32_bf16(a0[k], b0h, acc[k][0], 0, 0, 0);
                    acc[k][1] = __builtin_amdgcn_mfma_f32_16x16x32_bf16(a0[k], b1h, acc[k][1], 0, 0, 0);
                }
            }
        }
    }

#pragma unroll
    for (int k = 0; k < 5; k++) {
        int tile = wl + 4 * k;
#pragma unroll
        for (int j = 0; j < 2; j++)
#pragma unroll
            for (int reg = 0; reg < 4; reg++) {
                int prow = 16 * tile + 4 * g + reg;
                if (prow < 289)
                    atomicAdd(&corr[((size_t)m * 304 + prow) * 64 + (nb + j) * 16 + r],
                              acc[k][j][reg]);
            }
    }
#undef STAGE_SAT
}

// ---------- K2: argmax + similarity. grid 4096 = (m,n); block 64 ----------
__global__ __launch_bounds__(64) void argsim(const float* __restrict__ corr,
                                             const float* __restrict__ win2,
                                             const float* __restrict__ gn2,
                                             float* __restrict__ out,
                                             int* __restrict__ idxb) {
    int b = blockIdx.x, m = b >> 6, n = b & 63, lane = threadIdx.x;
    float bv = -3.0e38f;
    int bi = 1 << 30;
    for (int k = 0; k < 5; k++) {
        int p = lane + 64 * k;
        if (p < 289) {
            float v = corr[((size_t)m * 304 + p) * 64 + n];
            if (v > bv) { bv = v; bi = p; }   // ascending p: strict > = first occurrence
        }
    }
    for (int off = 32; off; off >>= 1) {
        float ov = __shfl_down(bv, off);
        int oi = __shfl_down(bi, off);
        if (ov > bv || (ov == bv && oi < bi)) { bv = ov; bi = oi; }
    }
    if (lane == 0) {
        float np = sqrtf(win2[m * 289 + bi]);
        float ng = sqrtf(gn2[n]);
        out[b] = bv / (fmaxf(np, 1e-12f) * fmaxf(ng, 1e-12f));
        idxb[b] = bi;
    }
}

// ---------- K3: winning patch for (63,63). grid 144; block 256 ----------
__global__ __launch_bounds__(256) void copy_patch(const float* __restrict__ sat,
                                                  const int* __restrict__ idxb,
                                                  float* __restrict__ out) {
    int fidx = idxb[4095];
    int hy = fidx / 17, wx = fidx % 17;
    int e = blockIdx.x * 256 + threadIdx.x;   // < 36864
    int c = e / 576;
    int rem = e - c * 576;
    int rr = rem / 24, col = rem - rr * 24;
    out[4096 + e] = sat[(size_t)(63 * 64 + c) * 4096 + (12 + hy + rr) * 64 + 12 + wx + col];
}

extern "C" void kernel_launch(void* const* d_in, const int* in_sizes, int n_in,
                              void* d_out, int out_size, void* d_ws, size_t ws_size,
                              hipStream_t stream) {
    const float* grd = (const float*)d_in[0];
    const float* sat = (const float*)d_in[1];
    float* out = (float*)d_out;

    float* wsf = (float*)d_ws;
    __hip_bfloat16* sth = (__hip_bfloat16*)(wsf + SATT_HI);
    __hip_bfloat16* stl = (__hip_bfloat16*)(wsf + SATT_LO);
    __hip_bfloat16* gth = (__hip_bfloat16*)(wsf + GRDT_HI);
    __hip_bfloat16* gtl = (__hip_bfloat16*)(wsf + GRDT_LO);
    float* corr = wsf + CORR_O;
    float* win2 = wsf + WIN2_O;
    float* gn2  = wsf + GN2_O;
    int*   idxb = (int*)(wsf + IDX_O);

    hipMemsetAsync(corr, 0, (size_t)64 * 304 * 64 * sizeof(float), stream);
    make_satT<<<2560, 256, 0, stream>>>(sat, sth, stl);
    make_grdT<<<256, 256, 0, stream>>>(grd, gth, gtl);
    make_win2<<<64, 256, 0, stream>>>(sat, win2);
    make_gn2<<<64, 256, 0, stream>>>(grd, gn2);
    corr_mfma<<<512, 512, 0, stream>>>(sth, stl, gth, gtl, corr);
    argsim<<<4096, 64, 0, stream>>>(corr, win2, gn2, out, idxb);
    copy_patch<<<144, 256, 0, stream>>>(sat, idxb, out);
}

// Round 13
// 231.254 us; speedup vs baseline: 2.0237x; 2.0237x over previous
//
#include <hip/hip_runtime.h>
#include <hip/hip_bf16.h>
#include <math.h>

// Shapes: grd (N=64,C=64,24,24), sat (M=64,C=64,64,64); crop sat[:,:,12:52,12:52] (40x40)
// corr (64,64,17,17); out: [0,4096) similarity f32, [4096,40960) sat_f (64,24,24) f32.
//
// Round-13 design: SINGLE bf16-product corr (error sigma~0.5 on corr~N(0,192): only
// near-ties flip; sim error <2e-4 << 0.085). sat_f(63,63) argmax made EXACT via a
// fp32 rescore kernel. Corr uses 32x32x16 MFMA (2x FLOP per operand byte vs 16x16)
// to break the LDS-bandwidth wall diagnosed in rounds 8-12.

typedef float f32x16 __attribute__((ext_vector_type(16)));
typedef short short8 __attribute__((ext_vector_type(8)));

// ws layout (float words)
#define SATT_H 0u          // bf16 [m][1600 pix][64 c] = 6,553,600 bf16 = 3,276,800 f
#define GRDT_H 3276800u    // bf16 [ij=576][n=64][c=64] = 2,359,296 bf16 = 1,179,648 f
#define CORR_O 4456448u    // f32 [m][304][64] = 1,245,184 f
#define WIN2_O 5701632u    // f32 [m][289]
#define GN2_O  5720128u    // f32 [64]
#define IDX_O  5720192u    // int [4096] (1024 f)
#define CEX_O  5721216u    // f32 [289]

// Injective LDS address transform (used identically on write and read):
// XOR row bits (6,7,8) into chunk bits (4,5,6). For 64-B rows this spreads any
// 32-consecutive-row b128 fragment read across all 8 bank groups (balanced).
#define SWZ64(off) ((off) ^ ((((off) >> 6) & 7) << 4))

// ---------- T1: satT bf16, channel-last. grid 2560 = (m, r); block 256 ----------
__global__ __launch_bounds__(256) void make_satT(const float* __restrict__ sat,
                                                 __hip_bfloat16* __restrict__ sth) {
    __shared__ __hip_bfloat16 th[40 * 66];
    int m = blockIdx.x / 40, r = blockIdx.x % 40;
    int tid = threadIdx.x;
    const float* base = sat + (size_t)m * 262144 + (12 + r) * 64 + 12;
    for (int k = 0; k < 10; k++) {
        int idx = tid + 256 * k;          // 2560 = 64c * 40w
        int c = idx / 40, w2 = idx % 40;
        th[w2 * 66 + c] = __float2bfloat16(base[c * 4096 + w2]);
    }
    __syncthreads();
    __hip_bfloat16* dh = sth + (size_t)m * 102400 + r * 2560;
    for (int k = 0; k < 10; k++) {
        int idx = tid + 256 * k;          // idx = w*64 + c
        int w2 = idx >> 6, c = idx & 63;
        dh[idx] = th[w2 * 66 + c];
    }
}

// ---------- T2: grdT bf16 [ij][n][c]. grid 128 = (n, c-half); block 256 ----------
__global__ __launch_bounds__(256) void make_grdT(const float* __restrict__ grd,
                                                 __hip_bfloat16* __restrict__ gth) {
    __shared__ __hip_bfloat16 t[32 * 577];
    int bid = blockIdx.x;
    int n = bid >> 1, ch = bid & 1;
    int tid = threadIdx.x;
    const float* src = grd + (size_t)n * 36864 + ch * 32 * 576;
    for (int k = 0; k < 72; k++) {
        int idx = tid + 256 * k;          // idx = cl*576 + ij
        int cl = idx / 576, ij = idx % 576;
        t[cl * 577 + ij] = __float2bfloat16(src[idx]);
    }
    __syncthreads();
    for (int k = 0; k < 72; k++) {
        int idx = tid + 256 * k;          // idx = ij*32 + cl
        int ij = idx >> 5, cl = idx & 31;
        gth[(size_t)ij * 4096 + n * 64 + ch * 32 + cl] = t[cl * 577 + ij];
    }
}

// ---------- N1: patch-window norms^2 via separable sums. grid 64 (m) ----------
__global__ __launch_bounds__(256) void make_win2(const float* __restrict__ sat,
                                                 float* __restrict__ win2) {
    __shared__ float S2[40][41];
    __shared__ float RS[40][18];
    int m = blockIdx.x, tid = threadIdx.x;
    const float* base = sat + (size_t)m * 262144;
    for (int k = 0; k < 7; k++) {
        int idx = tid + 256 * k;
        if (idx < 1600) {
            int r = idx / 40, w2 = idx % 40;
            float s = 0.0f;
            for (int c = 0; c < 64; c++) {
                float v = base[c * 4096 + (12 + r) * 64 + 12 + w2];
                s += v * v;
            }
            S2[r][w2] = s;
        }
    }
    __syncthreads();
    for (int k = 0; k < 3; k++) {
        int idx = tid + 256 * k;
        if (idx < 680) {
            int r = idx / 17, x = idx % 17;
            float s = 0.0f;
            for (int j = 0; j < 24; j++) s += S2[r][x + j];
            RS[r][x] = s;
        }
    }
    __syncthreads();
    for (int k = 0; k < 2; k++) {
        int idx = tid + 256 * k;
        if (idx < 289) {
            int y = idx / 17, x = idx % 17;
            float s = 0.0f;
            for (int i2 = 0; i2 < 24; i2++) s += RS[y + i2][x];
            win2[m * 289 + idx] = s;
        }
    }
}

// ---------- N2: ||grd_n||^2. grid 64 (n) ----------
__global__ __launch_bounds__(256) void make_gn2(const float* __restrict__ grd,
                                                float* __restrict__ gn2) {
    int n = blockIdx.x, tid = threadIdx.x;
    const float* g = grd + (size_t)n * 36864;
    float s = 0.0f;
    for (int k = 0; k < 144; k++) {
        float v = g[tid + 256 * k];
        s += v * v;
    }
    for (int off = 32; off; off >>= 1) s += __shfl_down(s, off);
    __shared__ float red[4];
    if ((tid & 63) == 0) red[tid >> 6] = s;
    __syncthreads();
    if (tid == 0) gn2[n] = red[0] + red[1] + red[2] + red[3];
}

// ---------- K1: MFMA corr (32x32x16, single product). grid 512; block 512 ----------
// p: 289 -> 12 tiles of 32 (tiles 10,11 pure ghost; loads clamp to p=288, stores
// guarded by prow<289). n: 2 tiles of 32. Wave w: n-tile (w&1), p-tiles
// {w>>1, (w>>1)+4, (w>>1)+8} (uniform T=3, all compile-time). Per cc (2 chunks of
// 32 c): satW [760 pix][32 c] staged once; per ij: Bl [64 n][32 c] (4 KB) staged
// double-buffered with 2-deep register prefetch; K = 2 steps of 16.
// K-enumeration between A and B frags is self-consistent (dot is k-permutation
// invariant), M/N = lane&31, C/D layout per verified m74/m101 mapping.
__global__ __launch_bounds__(512, 4) void corr_mfma(const __hip_bfloat16* __restrict__ sth,
                                                    const __hip_bfloat16* __restrict__ gth,
                                                    float* __restrict__ corr) {
    __shared__ __align__(16) __hip_bfloat16 satW[760 * 32];   // 48,640 B
    __shared__ __align__(16) __hip_bfloat16 Bl[2][64 * 32];   // 2 x 4,096 B

    int bid = blockIdx.x;
    int xcd = bid & 7, slot = bid >> 3;            // XCD-aware: 8 m per XCD
    int m = xcd * 8 + (slot >> 3), iq = slot & 7;  // iq = i-slice (3 rows)
    int tid = threadIdx.x;
    int w = tid >> 6, l = tid & 63;
    int ln31 = l & 31, h = l >> 5;
    int ntile = w & 1, pgrp = w >> 1;

    int rowbase[3];
#pragma unroll
    for (int t = 0; t < 3; t++) {
        int p = (pgrp + 4 * t) * 32 + ln31;
        if (p > 288) p = 288;                      // ghost rows read a valid pixel
        rowbase[t] = (p / 17) * 40 + (p % 17);
    }
    f32x16 acc[3];
#pragma unroll
    for (int t = 0; t < 3; t++) acc[t] = (f32x16)0.0f;

    const __hip_bfloat16* satb = sth + (size_t)m * 102400 + iq * 7680;
    // B staging (threads 0-255): one float4 per thread per ij.
    size_t gb = (size_t)(iq * 72) * 4096 + (tid >> 2) * 64 + (tid & 3) * 8;
    int bdst = SWZ64((tid & 255) * 16);
    // B fragment read offsets (per Kstep).
    int bro[2];
#pragma unroll
    for (int ks = 0; ks < 2; ks++)
        bro[ks] = SWZ64((ntile * 32 + ln31) * 64 + ks * 32 + h * 16);

#pragma unroll
    for (int cc = 0; cc < 2; cc++) {
        __syncthreads();                           // prior satW reads done
        // stage satW for this c-chunk: 3040 16-B slots
#pragma unroll
        for (int k2 = 0; k2 < 6; k2++) {
            int idx = tid + 512 * k2;
            if (idx < 3040) {
                float4 v = *(const float4*)(satb + (idx >> 2) * 64 + cc * 32 + (idx & 3) * 8);
                *(float4*)((char*)satW + SWZ64(idx * 16)) = v;
            }
        }
        float4 vnext;
        if (tid < 256) {
            float4 v0 = *(const float4*)(gth + gb + cc * 32);                 // ij 0
            *(float4*)((char*)&Bl[0][0] + bdst) = v0;
            vnext = *(const float4*)(gth + gb + 4096 + cc * 32);              // ij 1
        }
        __syncthreads();

        for (int ijl = 0; ijl < 72; ijl++) {
            int buf = ijl & 1;
            if (tid < 256 && ijl + 1 < 72) {
                *(float4*)((char*)&Bl[buf ^ 1][0] + bdst) = vnext;            // data(ij+1)
                if (ijl + 2 < 72)
                    vnext = *(const float4*)(gth + gb + (size_t)(ijl + 2) * 4096 + cc * 32);
            }
            int pixoff = (ijl / 24) * 40 + (ijl % 24);
#pragma unroll
            for (int ks = 0; ks < 2; ks++) {
                short8 bf = *(const short8*)((const char*)&Bl[buf][0] + bro[ks]);
#pragma unroll
                for (int t = 0; t < 3; t++) {
                    int pix = rowbase[t] + pixoff;
                    int ao = pix * 64 + ks * 32 + h * 16;
                    short8 af = *(const short8*)((const char*)satW + (ao ^ ((pix & 7) << 4)));
                    acc[t] = __builtin_amdgcn_mfma_f32_32x32x16_bf16(af, bf, acc[t], 0, 0, 0);
                }
            }
            __syncthreads();
        }
    }

#pragma unroll
    for (int t = 0; t < 3; t++) {
        int tile = pgrp + 4 * t;
#pragma unroll
        for (int q = 0; q < 16; q++) {
            int prow = tile * 32 + (q & 3) + 8 * (q >> 2) + 4 * h;
            if (prow < 289)
                atomicAdd(&corr[((size_t)m * 304 + prow) * 64 + ntile * 32 + ln31], acc[t][q]);
        }
    }
}

// ---------- K2: argmax + similarity. grid 4096 = (m,n); block 64 ----------
__global__ __launch_bounds__(64) void argsim(const float* __restrict__ corr,
                                             const float* __restrict__ win2,
                                             const float* __restrict__ gn2,
                                             float* __restrict__ out,
                                             int* __restrict__ idxb) {
    int b = blockIdx.x, m = b >> 6, n = b & 63, lane = threadIdx.x;
    float bv = -3.0e38f;
    int bi = 1 << 30;
    for (int k = 0; k < 5; k++) {
        int p = lane + 64 * k;
        if (p < 289) {
            float v = corr[((size_t)m * 304 + p) * 64 + n];
            if (v > bv) { bv = v; bi = p; }   // ascending p: strict > = first occurrence
        }
    }
    for (int off = 32; off; off >>= 1) {
        float ov = __shfl_down(bv, off);
        int oi = __shfl_down(bi, off);
        if (ov > bv || (ov == bv && oi < bi)) { bv = ov; bi = oi; }
    }
    if (lane == 0) {
        float np = sqrtf(win2[m * 289 + bi]);
        float ng = sqrtf(gn2[n]);
        out[b] = bv / (fmaxf(np, 1e-12f) * fmaxf(ng, 1e-12f));
        idxb[b] = bi;
    }
}

// ---------- K3a: exact fp32 corr for (m,n)=(63,63). grid 289; block 256 ----------
__global__ __launch_bounds__(256) void exact63(const float* __restrict__ sat,
                                               const float* __restrict__ grd,
                                               float* __restrict__ correx) {
    int p = blockIdx.x;
    int hy = p / 17, wx = p % 17;
    int tid = threadIdx.x;
    const float* satm = sat + (size_t)63 * 262144;
    const float* grdn = grd + (size_t)63 * 36864;
    float dot = 0.0f;
    for (int e = tid; e < 36864; e += 256) {
        int c = e / 576, rem = e - c * 576;
        int i = rem / 24, j = rem - i * 24;
        dot += satm[c * 4096 + (12 + hy + i) * 64 + 12 + wx + j] * grdn[e];
    }
    for (int off = 32; off; off >>= 1) dot += __shfl_down(dot, off);
    __shared__ float red[4];
    if ((tid & 63) == 0) red[tid >> 6] = dot;
    __syncthreads();
    if (tid == 0) correx[p] = red[0] + red[1] + red[2] + red[3];
}

// ---------- K3b: fix (63,63) argmax + sim from exact values. grid 1; block 64 ----------
__global__ __launch_bounds__(64) void fix63(const float* __restrict__ correx,
                                            const float* __restrict__ win2,
                                            const float* __restrict__ gn2,
                                            float* __restrict__ out,
                                            int* __restrict__ idxb) {
    int lane = threadIdx.x;
    float bv = -3.0e38f;
    int bi = 1 << 30;
    for (int k = 0; k < 5; k++) {
        int p = lane + 64 * k;
        if (p < 289) {
            float v = correx[p];
            if (v > bv) { bv = v; bi = p; }
        }
    }
    for (int off = 32; off; off >>= 1) {
        float ov = __shfl_down(bv, off);
        int oi = __shfl_down(bi, off);
        if (ov > bv || (ov == bv && oi < bi)) { bv = ov; bi = oi; }
    }
    if (lane == 0) {
        out[4095] = bv / (fmaxf(sqrtf(win2[63 * 289 + bi]), 1e-12f) *
                          fmaxf(sqrtf(gn2[63]), 1e-12f));
        idxb[4095] = bi;
    }
}

// ---------- K4: winning patch for (63,63). grid 144; block 256 ----------
__global__ __launch_bounds__(256) void copy_patch(const float* __restrict__ sat,
                                                  const int* __restrict__ idxb,
                                                  float* __restrict__ out) {
    int fidx = idxb[4095];
    int hy = fidx / 17, wx = fidx % 17;
    int e = blockIdx.x * 256 + threadIdx.x;   // < 36864
    int c = e / 576;
    int rem = e - c * 576;
    int rr = rem / 24, col = rem - rr * 24;
    out[4096 + e] = sat[(size_t)(63 * 64 + c) * 4096 + (12 + hy + rr) * 64 + 12 + wx + col];
}

extern "C" void kernel_launch(void* const* d_in, const int* in_sizes, int n_in,
                              void* d_out, int out_size, void* d_ws, size_t ws_size,
                              hipStream_t stream) {
    const float* grd = (const float*)d_in[0];
    const float* sat = (const float*)d_in[1];
    float* out = (float*)d_out;

    float* wsf = (float*)d_ws;
    __hip_bfloat16* sth = (__hip_bfloat16*)(wsf + SATT_H);
    __hip_bfloat16* gth = (__hip_bfloat16*)(wsf + GRDT_H);
    float* corr = wsf + CORR_O;
    float* win2 = wsf + WIN2_O;
    float* gn2  = wsf + GN2_O;
    int*   idxb = (int*)(wsf + IDX_O);
    float* cex  = wsf + CEX_O;

    hipMemsetAsync(corr, 0, (size_t)64 * 304 * 64 * sizeof(float), stream);
    make_satT<<<2560, 256, 0, stream>>>(sat, sth);
    make_grdT<<<128, 256, 0, stream>>>(grd, gth);
    make_win2<<<64, 256, 0, stream>>>(sat, win2);
    make_gn2<<<64, 256, 0, stream>>>(grd, gn2);
    corr_mfma<<<512, 512, 0, stream>>>(sth, gth, corr);
    argsim<<<4096, 64, 0, stream>>>(corr, win2, gn2, out, idxb);
    exact63<<<289, 256, 0, stream>>>(sat, grd, cex);
    fix63<<<1, 64, 0, stream>>>(cex, win2, gn2, out, idxb);
    copy_patch<<<144, 256, 0, stream>>>(sat, idxb, out);
}